// Round 1
// baseline (3759.841 us; speedup 1.0000x reference)
//
#include <hip/hip_runtime.h>

// Problem constants (B=8, C=128, N=H*W=16384, NH=8, HD=16, D=128)
#define N_SEQ 16384
#define TSTR 65    // padded LDS stride for [feat][n] tiles (conflict-free column reads)
#define FSTR 132   // padded LDS stride for [n][feat] transposed tiles (float4-aligned)
#define EPSF 1e-6f

__device__ __forceinline__ int rfl(int x){ return __builtin_amdgcn_readfirstlane(x); }

// Load a [128][64] feature-major tile from global [C][N] slab into LDS.
__device__ __forceinline__ void load_tile(const float* __restrict__ src, float* __restrict__ Ts,
                                          int lane, int rb){
  #pragma unroll
  for (int rr = 0; rr < 16; ++rr){
    int c = rb + rr;
    Ts[c*TSTR + lane] = src[(size_t)c*N_SEQ + lane];
  }
}

// Ys[128][64] = (relu?)(W[128x128] @ Xs[128][64]) (+eps if RELU)
template<bool RELU>
__device__ __forceinline__ void mm_WX(const float* __restrict__ W, const float* __restrict__ Xs,
                                      float* __restrict__ Ys, int lane, int rb){
  float a[16];
  #pragma unroll
  for (int r = 0; r < 16; ++r) a[r] = 0.f;
  #pragma unroll 1
  for (int k0 = 0; k0 < 128; k0 += 8){
    float x[8];
    #pragma unroll
    for (int j = 0; j < 8; ++j) x[j] = Xs[(k0+j)*TSTR + lane];
    #pragma unroll
    for (int r = 0; r < 16; ++r){
      const float* wr = W + (rb+r)*128 + k0;   // wave-uniform -> scalar loads
      #pragma unroll
      for (int j = 0; j < 8; ++j) a[r] = fmaf(wr[j], x[j], a[r]);
    }
  }
  #pragma unroll
  for (int r = 0; r < 16; ++r)
    Ys[(rb+r)*TSTR + lane] = RELU ? (fmaxf(a[r], 0.f) + EPSF) : a[r];
}

// Transposed-output variant for pass 1: Yt[n][feat]  (feat contiguous -> float4 KV reads later)
template<bool RELU>
__device__ __forceinline__ void mm_WX_T(const float* __restrict__ W, const float* __restrict__ Xs,
                                        float* __restrict__ Yt, int lane, int rb){
  float a[16];
  #pragma unroll
  for (int r = 0; r < 16; ++r) a[r] = 0.f;
  #pragma unroll 1
  for (int k0 = 0; k0 < 128; k0 += 8){
    float x[8];
    #pragma unroll
    for (int j = 0; j < 8; ++j) x[j] = Xs[(k0+j)*TSTR + lane];
    #pragma unroll
    for (int r = 0; r < 16; ++r){
      const float* wr = W + (rb+r)*128 + k0;
      #pragma unroll
      for (int j = 0; j < 8; ++j) a[r] = fmaf(wr[j], x[j], a[r]);
    }
  }
  #pragma unroll
  for (int r = 0; r < 16; ++r)
    a[r] = RELU ? (fmaxf(a[r], 0.f) + EPSF) : a[r];
  float4* dst = reinterpret_cast<float4*>(&Yt[lane*FSTR + rb]);
  dst[0] = make_float4(a[0],a[1],a[2],a[3]);
  dst[1] = make_float4(a[4],a[5],a[6],a[7]);
  dst[2] = make_float4(a[8],a[9],a[10],a[11]);
  dst[3] = make_float4(a[12],a[13],a[14],a[15]);
}

// In-place: Ts = Ts + W @ Xs   (each element read/written only by its owning thread)
__device__ __forceinline__ void mm_WX_addT(const float* __restrict__ W, const float* __restrict__ Xs,
                                           float* __restrict__ Ts, int lane, int rb){
  float a[16];
  #pragma unroll
  for (int r = 0; r < 16; ++r) a[r] = Ts[(rb+r)*TSTR + lane];
  #pragma unroll 1
  for (int k0 = 0; k0 < 128; k0 += 8){
    float x[8];
    #pragma unroll
    for (int j = 0; j < 8; ++j) x[j] = Xs[(k0+j)*TSTR + lane];
    #pragma unroll
    for (int r = 0; r < 16; ++r){
      const float* wr = W + (rb+r)*128 + k0;
      #pragma unroll
      for (int j = 0; j < 8; ++j) a[r] = fmaf(wr[j], x[j], a[r]);
    }
  }
  #pragma unroll
  for (int r = 0; r < 16; ++r) Ts[(rb+r)*TSTR + lane] = a[r];
}

// acc[16] += Wout[:, coloff:coloff+128] @ Xs   (Wout row stride 384)
__device__ __forceinline__ void mm_WX_acc(const float* __restrict__ W, int coloff,
                                          const float* __restrict__ Xs, float* __restrict__ acc,
                                          int lane, int rb){
  #pragma unroll 1
  for (int k0 = 0; k0 < 128; k0 += 8){
    float x[8];
    #pragma unroll
    for (int j = 0; j < 8; ++j) x[j] = Xs[(k0+j)*TSTR + lane];
    #pragma unroll
    for (int r = 0; r < 16; ++r){
      const float* wr = W + (rb+r)*384 + coloff + k0;
      #pragma unroll
      for (int j = 0; j < 8; ++j) acc[r] = fmaf(wr[j], x[j], acc[r]);
    }
  }
}

// U[feat][n] = sum over kv-sources s of z_s(n,h) * (qh(n,h,:) @ KV_s[h])
// thread: n = lane, head h = wave id. KV/Ks reads are wave-uniform (scalar).
__device__ __forceinline__ void attn_U(int s1, int s2, int b,
                                       const float* __restrict__ Qs, float* __restrict__ Us,
                                       const float* __restrict__ kvf, const float* __restrict__ ksf,
                                       int lane, int h){
  float qh[16];
  #pragma unroll
  for (int d = 0; d < 16; ++d) qh[d] = Qs[(h*16+d)*TSTR + lane];
  float u[16];
  #pragma unroll
  for (int m = 0; m < 16; ++m) u[m] = 0.f;
  #pragma unroll 1
  for (int jj = 0; jj < 2; ++jj){
    int s = (jj == 0) ? s1 : s2;
    if (s < 0) break;
    const float* __restrict__ KV = kvf + (size_t)((s*8 + b)*8 + h)*256;
    const float* __restrict__ Ks = ksf + (size_t)((s*8 + b)*8 + h)*16;
    float den = EPSF;
    #pragma unroll
    for (int d = 0; d < 16; ++d) den = fmaf(qh[d], Ks[d], den);
    float z = 1.0f / den;
    #pragma unroll
    for (int m = 0; m < 16; ++m){
      float sa = 0.f;
      #pragma unroll
      for (int d = 0; d < 16; ++d) sa = fmaf(KV[d*16 + m], qh[d], sa);
      u[m] = fmaf(z, sa, u[m]);
    }
  }
  #pragma unroll
  for (int m = 0; m < 16; ++m) Us[(h*16+m)*TSTR + lane] = u[m];
}

// ---------------- Pass 1: partial KV[s][b][h][16][16] and Ks[s][b][h][16] per 1024-n chunk ----------
__global__ __launch_bounds__(512, 2) void k_pass1(const float* __restrict__ t1, const float* __restrict__ t2,
    const float* __restrict__ t3, const float* __restrict__ fs,
    const float* __restrict__ Wk, const float* __restrict__ Wv,
    float* __restrict__ pkv, float* __restrict__ pks){
  __shared__ float Ts[128*TSTR];
  __shared__ float KHt[64*FSTR];
  __shared__ float Vt[64*FSTR];
  int bid = blockIdx.x;
  int ch = bid & 15, b = (bid >> 4) & 7, s = bid >> 7;
  int lane = threadIdx.x & 63;
  int rb = rfl((int)threadIdx.x >> 6) << 4;   // wave-uniform row base
  int h = rb >> 4;
  int d = lane & 15, mg = lane >> 4;
  const float* src = (s == 0) ? t1 : (s == 1) ? t2 : (s == 2) ? t3 : fs;
  src += (size_t)b*128*N_SEQ + ch*1024;
  float kv0 = 0.f, kv1 = 0.f, kv2 = 0.f, kv3 = 0.f, ksum = 0.f;
  for (int tile = 0; tile < 16; ++tile){
    load_tile(src + tile*64, Ts, lane, rb);
    __syncthreads();
    mm_WX_T<true >(Wk, Ts, KHt, lane, rb);   // kh = relu(Wk@T)+eps, stored [n][feat]
    mm_WX_T<false>(Wv, Ts, Vt,  lane, rb);   // v  = Wv@T,           stored [n][feat]
    __syncthreads();
    #pragma unroll 4
    for (int n = 0; n < 64; ++n){
      float kh = KHt[n*FSTR + h*16 + d];
      float4 v4 = *reinterpret_cast<const float4*>(&Vt[n*FSTR + h*16 + mg*4]);
      kv0 = fmaf(kh, v4.x, kv0);
      kv1 = fmaf(kh, v4.y, kv1);
      kv2 = fmaf(kh, v4.z, kv2);
      kv3 = fmaf(kh, v4.w, kv3);
      ksum += kh;                 // only mg==0 lanes store this
    }
    __syncthreads();
  }
  size_t pb = (((size_t)(ch*4 + s)*8 + b)*8 + h)*256 + (size_t)d*16 + mg*4;
  pkv[pb+0] = kv0; pkv[pb+1] = kv1; pkv[pb+2] = kv2; pkv[pb+3] = kv3;
  if (mg == 0)
    pks[(((size_t)(ch*4 + s)*8 + b)*8 + h)*16 + d] = ksum;
}

// ---------------- Reduce partials over the 16 chunks -----------------------------------------------
__global__ void k_reduce(const float* __restrict__ pkv, const float* __restrict__ pks,
                         float* __restrict__ kvf, float* __restrict__ ksf){
  int i = blockIdx.x*256 + threadIdx.x;   // grid covers 65536 + 4096 exactly
  if (i < 65536){
    float a = 0.f;
    #pragma unroll
    for (int ch = 0; ch < 16; ++ch) a += pkv[(size_t)ch*65536 + i];
    kvf[i] = a;
  } else {
    int j = i - 65536;
    float a = 0.f;
    #pragma unroll
    for (int ch = 0; ch < 16; ++ch) a += pks[(size_t)ch*4096 + j];
    ksf[j] = a;
  }
}

// ---------------- Pass 2: fully fused per-n pipeline (stage A + stage B + Wout + fs) ---------------
__global__ __launch_bounds__(512, 2) void k_pass2(const float* __restrict__ t1, const float* __restrict__ t2,
    const float* __restrict__ t3, const float* __restrict__ fs,
    const float* __restrict__ Wq, const float* __restrict__ Wback, const float* __restrict__ Wout,
    const float* __restrict__ kvf, const float* __restrict__ ksf,
    float* __restrict__ outp){
  __shared__ float Ts[128*TSTR];
  __shared__ float Qs[128*TSTR];
  __shared__ float Us[128*TSTR];
  int bid = blockIdx.x;
  int b = bid >> 8, nb = bid & 255;
  int n0 = nb * 64;
  int lane = threadIdx.x & 63;
  int rb = rfl((int)threadIdx.x >> 6) << 4;
  int h = rb >> 4;
  float acc[16];
  #pragma unroll
  for (int r = 0; r < 16; ++r) acc[r] = 0.f;

  #pragma unroll 1
  for (int i = 0; i < 3; ++i){
    const float* src = (i == 0) ? t1 : (i == 1) ? t2 : t3;
    int s1 = (i == 0) ? 1 : 0;
    int s2 = (i == 2) ? 1 : 2;
    load_tile(src + (size_t)b*128*N_SEQ + n0, Ts, lane, rb);
    __syncthreads();
    mm_WX<true>(Wq, Ts, Qs, lane, rb);                   // qh_i = relu(Wq@T)+eps
    __syncthreads();
    attn_U(s1, s2, b, Qs, Us, kvf, ksf, lane, h);        // stage-A U (both kv sources fused)
    __syncthreads();
    mm_WX_addT(Wback, Us, Ts, lane, rb);                 // T <- t_ia
    __syncthreads();
    mm_WX<true>(Wq, Ts, Qs, lane, rb);                   // qh of t_ia
    __syncthreads();
    attn_U(3, -1, b, Qs, Us, kvf, ksf, lane, h);         // stage-B U (fusion kv)
    __syncthreads();
    mm_WX_addT(Wback, Us, Ts, lane, rb);                 // T <- t_if
    __syncthreads();
    mm_WX_acc(Wout, i*128, Ts, acc, lane, rb);           // acc += Wout_i @ t_if
    __syncthreads();                                     // before next i overwrites Ts
  }
  const float* fsp = fs + (size_t)b*128*N_SEQ + n0;
  float* op = outp + (size_t)b*128*N_SEQ + n0;
  #pragma unroll
  for (int r = 0; r < 16; ++r){
    int c = rb + r;
    op[(size_t)c*N_SEQ + lane] = acc[r] + fsp[(size_t)c*N_SEQ + lane];
  }
}

extern "C" void kernel_launch(void* const* d_in, const int* in_sizes, int n_in,
                              void* d_out, int out_size, void* d_ws, size_t ws_size,
                              hipStream_t stream){
  const float* t1 = (const float*)d_in[0];
  const float* t2 = (const float*)d_in[1];
  const float* t3 = (const float*)d_in[2];
  const float* fs = (const float*)d_in[3];
  const float* Wq = (const float*)d_in[4];
  const float* Wk = (const float*)d_in[5];
  const float* Wv = (const float*)d_in[6];
  const float* Wb = (const float*)d_in[7];
  const float* Wo = (const float*)d_in[8];
  float* outp = (float*)d_out;
  float* ws = (float*)d_ws;
  // ws layout (floats): final KV [65536] | final Ks [4096] | partial KV [16*65536] | partial Ks [16*4096]
  float* kvf = ws;
  float* ksf = ws + 65536;
  float* pkv = ws + 69632;
  float* pks = ws + 69632 + 16*65536;

  k_pass1 <<<dim3(512),  dim3(512), 0, stream>>>(t1, t2, t3, fs, Wk, Wv, pkv, pks);
  k_reduce<<<dim3(272),  dim3(256), 0, stream>>>(pkv, pks, kvf, ksf);
  k_pass2 <<<dim3(2048), dim3(512), 0, stream>>>(t1, t2, t3, fs, Wq, Wb, Wo, kvf, ksf, outp);
}

// Round 2
// 2460.786 us; speedup vs baseline: 1.5279x; 1.5279x over previous
//
#include <hip/hip_runtime.h>

// Problem constants (B=8, C=128, N=H*W=16384, NH=8, HD=16, D=128)
#define N_SEQ 16384
#define TSTR 65    // padded LDS stride for [feat][n] fp32 tiles (conflict-free column reads)
#define KSTR 132   // padded LDS stride (in u16) for [n][feat] bf16 tiles in pass 1
#define EPSF 1e-6f

typedef unsigned short u16;
typedef unsigned int   u32;

__device__ __forceinline__ int rfl(int x){ return __builtin_amdgcn_readfirstlane(x); }

__device__ __forceinline__ u16 f2bf(float x){            // round-to-nearest-even bf16
  u32 u = __float_as_uint(x);
  u32 r = u + 0x7fffu + ((u >> 16) & 1u);
  return (u16)(r >> 16);
}
__device__ __forceinline__ float bf2f(u16 v){ return __uint_as_float(((u32)v) << 16); }

// Load a [128][64] feature-major tile from global [C][N] slab into LDS.
__device__ __forceinline__ void load_tile(const float* __restrict__ src, float* __restrict__ Ts,
                                          int lane, int rb){
  #pragma unroll
  for (int rr = 0; rr < 16; ++rr){
    int c = rb + rr;
    Ts[c*TSTR + lane] = src[(size_t)c*N_SEQ + lane];
  }
}

// ---- pass 2: fused  q = relu(Wq@X)+eps  ->  U = sum_s z_s * (q @ KV_s)  -> Us (LDS) -------------
// Thread (lane, wave h) computes q for rows h*16..h*16+15 at col=lane, which is exactly the
// per-(n,head) fragment the attention step needs -> q and u never touch LDS.
__device__ __forceinline__ void qattn(const float* __restrict__ Wq,
                                      const float* __restrict__ Xs, float* __restrict__ Us,
                                      int s1, int s2, int b,
                                      const float* __restrict__ kvf, const float* __restrict__ ksf,
                                      int lane, int rb, int h){
  float q[16];
  #pragma unroll
  for (int r = 0; r < 16; ++r) q[r] = 0.f;
  #pragma unroll 1
  for (int k0 = 0; k0 < 128; k0 += 8){
    float x[8];
    #pragma unroll
    for (int j = 0; j < 8; ++j) x[j] = Xs[(k0+j)*TSTR + lane];
    #pragma unroll
    for (int r = 0; r < 16; ++r){
      const float* wr = Wq + (rb+r)*128 + k0;   // wave-uniform -> scalar loads
      #pragma unroll
      for (int j = 0; j < 8; ++j) q[r] = fmaf(wr[j], x[j], q[r]);
    }
  }
  #pragma unroll
  for (int r = 0; r < 16; ++r) q[r] = fmaxf(q[r], 0.f) + EPSF;

  float u[16];
  #pragma unroll
  for (int m = 0; m < 16; ++m) u[m] = 0.f;
  #pragma unroll 1
  for (int jj = 0; jj < 2; ++jj){
    int s = (jj == 0) ? s1 : s2;
    if (s < 0) break;
    const float* __restrict__ KV = kvf + (size_t)((s*8 + b)*8 + h)*256;
    const float* __restrict__ Ks = ksf + (size_t)((s*8 + b)*8 + h)*16;
    float den = EPSF;
    #pragma unroll
    for (int d = 0; d < 16; ++d) den = fmaf(q[d], Ks[d], den);
    float z = 1.0f / den;
    #pragma unroll
    for (int m = 0; m < 16; ++m){
      float sa = 0.f;
      #pragma unroll
      for (int d = 0; d < 16; ++d) sa = fmaf(KV[d*16 + m], q[d], sa);
      u[m] = fmaf(z, sa, u[m]);
    }
  }
  #pragma unroll
  for (int m = 0; m < 16; ++m) Us[(rb+m)*TSTR + lane] = u[m];
}

// In-place: Ts = Ts + W @ Xs
__device__ __forceinline__ void mm_WX_addT(const float* __restrict__ W, const float* __restrict__ Xs,
                                           float* __restrict__ Ts, int lane, int rb){
  float a[16];
  #pragma unroll
  for (int r = 0; r < 16; ++r) a[r] = Ts[(rb+r)*TSTR + lane];
  #pragma unroll 1
  for (int k0 = 0; k0 < 128; k0 += 8){
    float x[8];
    #pragma unroll
    for (int j = 0; j < 8; ++j) x[j] = Xs[(k0+j)*TSTR + lane];
    #pragma unroll
    for (int r = 0; r < 16; ++r){
      const float* wr = W + (rb+r)*128 + k0;
      #pragma unroll
      for (int j = 0; j < 8; ++j) a[r] = fmaf(wr[j], x[j], a[r]);
    }
  }
  #pragma unroll
  for (int r = 0; r < 16; ++r) Ts[(rb+r)*TSTR + lane] = a[r];
}

// acc[16] += Wout[:, coloff:coloff+128] @ Xs   (Wout row stride 384)
__device__ __forceinline__ void mm_WX_acc(const float* __restrict__ W, int coloff,
                                          const float* __restrict__ Xs, float* __restrict__ acc,
                                          int lane, int rb){
  #pragma unroll 1
  for (int k0 = 0; k0 < 128; k0 += 8){
    float x[8];
    #pragma unroll
    for (int j = 0; j < 8; ++j) x[j] = Xs[(k0+j)*TSTR + lane];
    #pragma unroll
    for (int r = 0; r < 16; ++r){
      const float* wr = W + (rb+r)*384 + coloff + k0;
      #pragma unroll
      for (int j = 0; j < 8; ++j) acc[r] = fmaf(wr[j], x[j], acc[r]);
    }
  }
}

// ---- pass 1: Y^T tile in bf16:  Yt[n][feat] = (relu?)(W @ Xs)  (feat contiguous, u16) ------------
template<bool RELU>
__device__ __forceinline__ void mm_WX_Tb(const float* __restrict__ W, const float* __restrict__ Xs,
                                         u16* __restrict__ Yt, int lane, int rb){
  float a[16];
  #pragma unroll
  for (int r = 0; r < 16; ++r) a[r] = 0.f;
  #pragma unroll 1
  for (int k0 = 0; k0 < 128; k0 += 8){
    float x[8];
    #pragma unroll
    for (int j = 0; j < 8; ++j) x[j] = Xs[(k0+j)*TSTR + lane];
    #pragma unroll
    for (int r = 0; r < 16; ++r){
      const float* wr = W + (rb+r)*128 + k0;
      #pragma unroll
      for (int j = 0; j < 8; ++j) a[r] = fmaf(wr[j], x[j], a[r]);
    }
  }
  #pragma unroll
  for (int r = 0; r < 16; ++r)
    a[r] = RELU ? (fmaxf(a[r], 0.f) + EPSF) : a[r];
  u32 p[8];
  #pragma unroll
  for (int j = 0; j < 8; ++j)
    p[j] = (u32)f2bf(a[2*j]) | ((u32)f2bf(a[2*j+1]) << 16);
  uint2* dst = reinterpret_cast<uint2*>(&Yt[lane*KSTR + rb]);  // 8B-aligned (264*lane + 32*r)
  dst[0] = make_uint2(p[0], p[1]);
  dst[1] = make_uint2(p[2], p[3]);
  dst[2] = make_uint2(p[4], p[5]);
  dst[3] = make_uint2(p[6], p[7]);
}

// ---------------- Pass 1: partial KV[s][b][h][16][16] and Ks[s][b][h][16] per 1024-n chunk --------
__global__ __launch_bounds__(512, 4) void k_pass1(const float* __restrict__ t1, const float* __restrict__ t2,
    const float* __restrict__ t3, const float* __restrict__ fs,
    const float* __restrict__ Wk, const float* __restrict__ Wv,
    float* __restrict__ pkv, float* __restrict__ pks){
  __shared__ float Ts[128*TSTR];     // 33280 B
  __shared__ u16  KHt[64*KSTR];      // 16896 B
  __shared__ u16  Vt [64*KSTR];      // 16896 B   -> total 67072 B -> 2 blocks/CU
  int bid = blockIdx.x;
  int ch = bid & 15, b = (bid >> 4) & 7, s = bid >> 7;
  int lane = threadIdx.x & 63;
  int rb = rfl((int)threadIdx.x >> 6) << 4;   // wave-uniform row base
  int h = rb >> 4;
  int d = lane & 15, mg = lane >> 4;
  const float* src = (s == 0) ? t1 : (s == 1) ? t2 : (s == 2) ? t3 : fs;
  src += (size_t)b*128*N_SEQ + ch*1024;
  float kv0 = 0.f, kv1 = 0.f, kv2 = 0.f, kv3 = 0.f, ksum = 0.f;
  for (int tile = 0; tile < 16; ++tile){
    load_tile(src + tile*64, Ts, lane, rb);
    __syncthreads();
    mm_WX_Tb<true >(Wk, Ts, KHt, lane, rb);   // kh = relu(Wk@T)+eps, bf16 [n][feat]
    mm_WX_Tb<false>(Wv, Ts, Vt,  lane, rb);   // v  = Wv@T,           bf16 [n][feat]
    __syncthreads();
    #pragma unroll 4
    for (int n = 0; n < 64; ++n){
      float kh = bf2f(KHt[n*KSTR + h*16 + d]);
      uint2 vv = *reinterpret_cast<const uint2*>(&Vt[n*KSTR + h*16 + mg*4]);
      kv0 = fmaf(kh, bf2f((u16)(vv.x & 0xffffu)), kv0);
      kv1 = fmaf(kh, bf2f((u16)(vv.x >> 16)),     kv1);
      kv2 = fmaf(kh, bf2f((u16)(vv.y & 0xffffu)), kv2);
      kv3 = fmaf(kh, bf2f((u16)(vv.y >> 16)),     kv3);
      ksum += kh;                 // only mg==0 lanes store this
    }
    __syncthreads();
  }
  size_t pb = (((size_t)(ch*4 + s)*8 + b)*8 + h)*256 + (size_t)d*16 + mg*4;
  pkv[pb+0] = kv0; pkv[pb+1] = kv1; pkv[pb+2] = kv2; pkv[pb+3] = kv3;
  if (mg == 0)
    pks[(((size_t)(ch*4 + s)*8 + b)*8 + h)*16 + d] = ksum;
}

// ---------------- Reduce partials over the 16 chunks ----------------------------------------------
__global__ void k_reduce(const float* __restrict__ pkv, const float* __restrict__ pks,
                         float* __restrict__ kvf, float* __restrict__ ksf){
  int i = blockIdx.x*256 + threadIdx.x;   // grid covers 65536 + 4096 exactly
  if (i < 65536){
    float a = 0.f;
    #pragma unroll
    for (int ch = 0; ch < 16; ++ch) a += pkv[(size_t)ch*65536 + i];
    kvf[i] = a;
  } else {
    int j = i - 65536;
    float a = 0.f;
    #pragma unroll
    for (int ch = 0; ch < 16; ++ch) a += pks[(size_t)ch*4096 + j];
    ksf[j] = a;
  }
}

// ---------------- Pass 2: fully fused per-n pipeline (stage A + stage B + Wout + fs) --------------
__global__ __launch_bounds__(512, 4) void k_pass2(const float* __restrict__ t1, const float* __restrict__ t2,
    const float* __restrict__ t3, const float* __restrict__ fs,
    const float* __restrict__ Wq, const float* __restrict__ Wback, const float* __restrict__ Wout,
    const float* __restrict__ kvf, const float* __restrict__ ksf,
    float* __restrict__ outp){
  __shared__ float Ts[128*TSTR];     // 33280 B
  __shared__ float Us[128*TSTR];     // 33280 B -> total 66560 B -> 2 blocks/CU
  int bid = blockIdx.x;
  int b = bid >> 8, nb = bid & 255;
  int n0 = nb * 64;
  int lane = threadIdx.x & 63;
  int rb = rfl((int)threadIdx.x >> 6) << 4;
  int h = rb >> 4;
  float acc[16];
  #pragma unroll
  for (int r = 0; r < 16; ++r) acc[r] = 0.f;

  #pragma unroll 1
  for (int i = 0; i < 3; ++i){
    const float* src = (i == 0) ? t1 : (i == 1) ? t2 : t3;
    int s1 = (i == 0) ? 1 : 0;
    int s2 = (i == 2) ? 1 : 2;
    load_tile(src + (size_t)b*128*N_SEQ + n0, Ts, lane, rb);
    __syncthreads();
    qattn(Wq, Ts, Us, s1, s2, b, kvf, ksf, lane, rb, h);   // stage-A: q (regs) -> U -> Us
    __syncthreads();
    mm_WX_addT(Wback, Us, Ts, lane, rb);                   // T <- t_ia
    __syncthreads();
    qattn(Wq, Ts, Us, 3, -1, b, kvf, ksf, lane, rb, h);    // stage-B: fusion kv
    __syncthreads();
    mm_WX_addT(Wback, Us, Ts, lane, rb);                   // T <- t_if
    __syncthreads();
    mm_WX_acc(Wout, i*128, Ts, acc, lane, rb);             // acc += Wout_i @ t_if
    __syncthreads();                                       // before next i overwrites Ts
  }
  const float* fsp = fs + (size_t)b*128*N_SEQ + n0;
  float* op = outp + (size_t)b*128*N_SEQ + n0;
  #pragma unroll
  for (int r = 0; r < 16; ++r){
    int c = rb + r;
    op[(size_t)c*N_SEQ + lane] = acc[r] + fsp[(size_t)c*N_SEQ + lane];
  }
}

extern "C" void kernel_launch(void* const* d_in, const int* in_sizes, int n_in,
                              void* d_out, int out_size, void* d_ws, size_t ws_size,
                              hipStream_t stream){
  const float* t1 = (const float*)d_in[0];
  const float* t2 = (const float*)d_in[1];
  const float* t3 = (const float*)d_in[2];
  const float* fs = (const float*)d_in[3];
  const float* Wq = (const float*)d_in[4];
  const float* Wk = (const float*)d_in[5];
  const float* Wv = (const float*)d_in[6];
  const float* Wb = (const float*)d_in[7];
  const float* Wo = (const float*)d_in[8];
  float* outp = (float*)d_out;
  float* ws = (float*)d_ws;
  // ws layout (floats): final KV [65536] | final Ks [4096] | partial KV [16*65536] | partial Ks [16*4096]
  float* kvf = ws;
  float* ksf = ws + 65536;
  float* pkv = ws + 69632;
  float* pks = ws + 69632 + 16*65536;

  k_pass1 <<<dim3(512),  dim3(512), 0, stream>>>(t1, t2, t3, fs, Wk, Wv, pkv, pks);
  k_reduce<<<dim3(272),  dim3(256), 0, stream>>>(pkv, pks, kvf, ksf);
  k_pass2 <<<dim3(2048), dim3(512), 0, stream>>>(t1, t2, t3, fs, Wq, Wb, Wo, kvf, ksf, outp);
}

// Round 3
// 305.890 us; speedup vs baseline: 12.2915x; 8.0447x over previous
//
#include <hip/hip_runtime.h>
#include <hip/hip_bf16.h>

// B=8, C=128, N=16384, NH=8, HD=16, D=128
#define N_SEQ 16384
#define EPSF 1e-6f
#define XS 136      // u16 stride for [n][feat] bf16 LDS tiles (16B-aligned rows)
#define KS1 72      // u16 stride for [feat][n] bf16 LDS tiles (pass1 kh/v), 144B rows

typedef unsigned short u16;
typedef unsigned int   u32;
typedef __attribute__((ext_vector_type(8))) __bf16 bf16x8;
typedef __attribute__((ext_vector_type(4))) float  f32x4;

union B8 { u32 w[4]; bf16x8 v; };

__device__ __forceinline__ int rfl(int x){ return __builtin_amdgcn_readfirstlane(x); }
__device__ __forceinline__ u16 f2b(float x){
  union { __hip_bfloat16 h; u16 u; } c; c.h = __float2bfloat16(x); return c.u;
}
__device__ __forceinline__ u32 pk2(float a, float b){
  return (u32)f2b(a) | ((u32)f2b(b) << 16);
}
#define MFMA(a,b,c) __builtin_amdgcn_mfma_f32_16x16x32_bf16((a),(b),(c),0,0,0)

// Pack A-fragments for a 16-row weight slice: out[ks*4+t], k = ks*32 + g*8 + j.
// Lane (g,m) supplies A[m][k] = W[row=base+m][koff + k].
__device__ __forceinline__ void load_wfrag(const float* __restrict__ W, int row, int ldw,
                                           int koff, int g, u32* out){
  #pragma unroll
  for (int ks = 0; ks < 4; ++ks){
    const float* p = W + (size_t)row*ldw + koff + ks*32 + g*8;
    float4 a0 = *reinterpret_cast<const float4*>(p);
    float4 a1 = *reinterpret_cast<const float4*>(p + 4);
    out[ks*4+0] = pk2(a0.x, a0.y);
    out[ks*4+1] = pk2(a0.z, a0.w);
    out[ks*4+2] = pk2(a1.x, a1.y);
    out[ks*4+3] = pk2(a1.z, a1.w);
  }
}

// q[nt] += Wfrag @ X   (X: [n][feat] bf16 LDS, stride XS; K=128; N=64 as 4 ntiles)
__device__ __forceinline__ void gemm16(const u32* wf, const u16* __restrict__ Xl,
                                       int m, int g, f32x4 q[4]){
  #pragma unroll
  for (int ks = 0; ks < 4; ++ks){
    B8 a; a.w[0]=wf[ks*4+0]; a.w[1]=wf[ks*4+1]; a.w[2]=wf[ks*4+2]; a.w[3]=wf[ks*4+3];
    #pragma unroll
    for (int nt = 0; nt < 4; ++nt){
      const bf16x8 bv = *reinterpret_cast<const bf16x8*>(&Xl[(nt*16+m)*XS + ks*32 + g*8]);
      q[nt] = MFMA(a.v, bv, q[nt]);
    }
  }
}

// One attention+Wback stage: T += Wback @ [ sum_s z_s * (qh @ KV_s) ],  qh = relu(Wq@T)+eps.
// Leaves updated T (f32 regs) and refreshed bf16 X tile in LDS. 2 barriers.
template<int NSRC>
__device__ __forceinline__ void stage(u16* Xl, u16* Ul, const u32* wqf,
    const float* __restrict__ Wback, const float* __restrict__ kvf,
    const float* __restrict__ ksf,
    int s1, int s2, int b, int w, int g, int m, int rb, float (&Treg)[4][4]){
  const int sA = ((s1*8 + b)*8 + w);
  const int sB = ((s2*8 + b)*8 + w);
  float4 ksA = *reinterpret_cast<const float4*>(ksf + sA*16 + 4*g);
  float4 ksB = ksA;
  B8 kA, kB;
  #pragma unroll
  for (int t = 0; t < 4; ++t){     // A[m][k] = KV[k][m] for k<16 (K zero-padded via B)
    const float* p = kvf + (size_t)sA*256 + ((g&1)*8 + 2*t)*16 + m;
    kA.w[t] = pk2(p[0], p[16]);
  }
  if (NSRC == 2){
    ksB = *reinterpret_cast<const float4*>(ksf + sB*16 + 4*g);
    #pragma unroll
    for (int t = 0; t < 4; ++t){
      const float* p = kvf + (size_t)sB*256 + ((g&1)*8 + 2*t)*16 + m;
      kB.w[t] = pk2(p[0], p[16]);
    }
  }
  // qh = relu(Wq @ X) + eps  (C/D regs: row rb+4g+r, col nt*16+m)
  f32x4 q[4];
  #pragma unroll
  for (int nt = 0; nt < 4; ++nt) q[nt] = (f32x4){0.f,0.f,0.f,0.f};
  gemm16(wqf, Xl, m, g, q);
  #pragma unroll
  for (int nt = 0; nt < 4; ++nt)
    #pragma unroll
    for (int r = 0; r < 4; ++r) q[nt][r] = fmaxf(q[nt][r], 0.f) + EPSF;
  // z_s(n, h=w) = 1/(qh . Ks_s + eps): partial over own 4 rows, reduce over lane-groups
  float z1[4], z2[4];
  #pragma unroll
  for (int nt = 0; nt < 4; ++nt){
    float p = q[nt][0]*ksA.x + q[nt][1]*ksA.y + q[nt][2]*ksA.z + q[nt][3]*ksA.w;
    p += __shfl_xor(p, 16); p += __shfl_xor(p, 32);
    z1[nt] = 1.0f / (p + EPSF);
  }
  if (NSRC == 2){
    #pragma unroll
    for (int nt = 0; nt < 4; ++nt){
      float p = q[nt][0]*ksB.x + q[nt][1]*ksB.y + q[nt][2]*ksB.z + q[nt][3]*ksB.w;
      p += __shfl_xor(p, 16); p += __shfl_xor(p, 32);
      z2[nt] = 1.0f / (p + EPSF);
    }
  }
  // pack qh (bf16 pairs along rows)
  u32 pq0[4], pq1[4];
  #pragma unroll
  for (int nt = 0; nt < 4; ++nt){
    pq0[nt] = pk2(q[nt][0], q[nt][1]);
    pq1[nt] = pk2(q[nt][2], q[nt][3]);
  }
  // PV: per nt build B[k=d][col] from own wave's qh via shuffles (K=16, pad to 32 with zeros)
  const int sl = (g&1)*32 + m;
  #pragma unroll
  for (int nt = 0; nt < 4; ++nt){
    u32 v0 = (u32)__shfl((int)pq0[nt], sl);
    u32 v1 = (u32)__shfl((int)pq1[nt], sl);
    u32 v2 = (u32)__shfl((int)pq0[nt], sl + 16);
    u32 v3 = (u32)__shfl((int)pq1[nt], sl + 16);
    if (g >= 2){ v0 = v1 = v2 = v3 = 0u; }
    B8 bb; bb.w[0]=v0; bb.w[1]=v1; bb.w[2]=v2; bb.w[3]=v3;
    const f32x4 z4 = (f32x4){0.f,0.f,0.f,0.f};
    f32x4 S1 = MFMA(kA.v, bb.v, z4);
    f32x4 Uv = S1 * z1[nt];
    if (NSRC == 2){
      f32x4 S2 = MFMA(kB.v, bb.v, z4);
      Uv += S2 * z2[nt];
    }
    *reinterpret_cast<uint2*>(&Ul[(nt*16+m)*XS + rb + 4*g]) =
      make_uint2(pk2(Uv[0], Uv[1]), pk2(Uv[2], Uv[3]));
  }
  // prefetch Wback A-frags before the barrier (hides L2 latency)
  u32 wbf[16];
  load_wfrag(Wback, rb + m, 128, 0, g, wbf);
  __syncthreads();
  // T += Wback @ U ; refresh X tile
  f32x4 t4[4];
  #pragma unroll
  for (int nt = 0; nt < 4; ++nt) t4[nt] = (f32x4){0.f,0.f,0.f,0.f};
  gemm16(wbf, Ul, m, g, t4);
  #pragma unroll
  for (int nt = 0; nt < 4; ++nt){
    #pragma unroll
    for (int r = 0; r < 4; ++r) Treg[nt][r] += t4[nt][r];
    *reinterpret_cast<uint2*>(&Xl[(nt*16+m)*XS + rb + 4*g]) =
      make_uint2(pk2(Treg[nt][0], Treg[nt][1]), pk2(Treg[nt][2], Treg[nt][3]));
  }
  __syncthreads();
}

// ---------------- Pass 1: partial KV/Ks per 1024-n chunk (MFMA) -----------------------------------
__global__ __launch_bounds__(512, 4) void k_pass1(const float* __restrict__ t1,
    const float* __restrict__ t2, const float* __restrict__ t3, const float* __restrict__ fs,
    const float* __restrict__ Wk, const float* __restrict__ Wv,
    float* __restrict__ pkv, float* __restrict__ pks){
  __shared__ u16 Xl [64*XS];     // 17408 B
  __shared__ u16 khl[128*KS1];   // 18432 B
  __shared__ u16 vl [128*KS1];   // 18432 B  -> 54272 B -> 2 blocks/CU
  int bid = blockIdx.x;
  int ch = bid & 15, b = (bid >> 4) & 7, s = bid >> 7;
  int tid = threadIdx.x, lane = tid & 63;
  int w = rfl(tid >> 6), rb = w*16;
  int g = lane >> 4, m = lane & 15;
  const float* src = (s==0)?t1:(s==1)?t2:(s==2)?t3:fs;
  src += (size_t)b*128*N_SEQ + ch*1024;
  u32 wkf[16], wvf[16];
  load_wfrag(Wk, rb + m, 128, 0, g, wkf);
  load_wfrag(Wv, rb + m, 128, 0, g, wvf);
  f32x4 kvacc = (f32x4){0.f,0.f,0.f,0.f};
  float ksump[4] = {0.f,0.f,0.f,0.f};
  #pragma unroll 1
  for (int tile = 0; tile < 16; ++tile){
    const float* sp = src + tile*64;
    #pragma unroll
    for (int rr = 0; rr < 8; ++rr){        // coalesced along n; packed u32 LDS writes
      int c = w*16 + rr*2;
      float f0 = sp[(size_t)c*N_SEQ + lane];
      float f1 = sp[(size_t)(c+1)*N_SEQ + lane];
      *reinterpret_cast<u32*>(&Xl[lane*XS + c]) = pk2(f0, f1);
    }
    __syncthreads();
    f32x4 kh[4], vv[4];
    #pragma unroll
    for (int nt = 0; nt < 4; ++nt){ kh[nt] = (f32x4){0.f,0.f,0.f,0.f}; vv[nt] = kh[nt]; }
    gemm16(wkf, Xl, m, g, kh);
    gemm16(wvf, Xl, m, g, vv);
    #pragma unroll
    for (int nt = 0; nt < 4; ++nt)
      #pragma unroll
      for (int r = 0; r < 4; ++r){
        float x = fmaxf(kh[nt][r], 0.f) + EPSF;   // kh = relu(.)+eps
        ksump[r] += x;
        khl[(rb + 4*g + r)*KS1 + nt*16 + m] = f2b(x);
        vl [(rb + 4*g + r)*KS1 + nt*16 + m] = f2b(vv[nt][r]);
      }
    __syncthreads();
    // KV_w += kh_w(16 x 64n) @ v_w^T : A[d][k=n], B[k=n][col=m-feat]
    #pragma unroll
    for (int ks2 = 0; ks2 < 2; ++ks2){
      const bf16x8 av = *reinterpret_cast<const bf16x8*>(&khl[(rb+m)*KS1 + ks2*32 + g*8]);
      const bf16x8 bv = *reinterpret_cast<const bf16x8*>(&vl [(rb+m)*KS1 + ks2*32 + g*8]);
      kvacc = MFMA(av, bv, kvacc);
    }
  }
  size_t pb = (((size_t)(ch*4 + s)*8 + b)*8 + w)*256;
  #pragma unroll
  for (int r = 0; r < 4; ++r)
    pkv[pb + (size_t)(4*g + r)*16 + m] = kvacc[r];
  #pragma unroll
  for (int r = 0; r < 4; ++r){
    float v2 = ksump[r];
    v2 += __shfl_xor(v2, 1); v2 += __shfl_xor(v2, 2);
    v2 += __shfl_xor(v2, 4); v2 += __shfl_xor(v2, 8);
    if (m == 0) pks[(((size_t)(ch*4 + s)*8 + b)*8 + w)*16 + 4*g + r] = v2;
  }
}

// ---------------- Reduce partials over the 16 chunks ----------------------------------------------
__global__ void k_reduce(const float* __restrict__ pkv, const float* __restrict__ pks,
                         float* __restrict__ kvf, float* __restrict__ ksf){
  int i = blockIdx.x*256 + threadIdx.x;
  if (i < 65536){
    float a = 0.f;
    #pragma unroll
    for (int ch = 0; ch < 16; ++ch) a += pkv[(size_t)ch*65536 + i];
    kvf[i] = a;
  } else {
    int j = i - 65536;
    float a = 0.f;
    #pragma unroll
    for (int ch = 0; ch < 16; ++ch) a += pks[(size_t)ch*4096 + j];
    ksf[j] = a;
  }
}

// ---------------- Pass 2: fused per-n pipeline, all GEMMs on MFMA ----------------------------------
__global__ __launch_bounds__(512, 4) void k_pass2(const float* __restrict__ t1,
    const float* __restrict__ t2, const float* __restrict__ t3, const float* __restrict__ fs,
    const float* __restrict__ Wq, const float* __restrict__ Wback, const float* __restrict__ Wout,
    const float* __restrict__ kvf, const float* __restrict__ ksf, float* __restrict__ outp){
  __shared__ u16 Xl[64*XS];   // 17408 B
  __shared__ u16 Ul[64*XS];   // 17408 B -> 34816 B -> 2 blocks/CU
  int bid = blockIdx.x;
  int b = bid >> 8, n0 = (bid & 255) * 64;
  int tid = threadIdx.x, lane = tid & 63;
  int w = rfl(tid >> 6), rb = w*16;
  int g = lane >> 4, m = lane & 15;
  u32 wqf[16];
  load_wfrag(Wq, rb + m, 128, 0, g, wqf);
  f32x4 oacc[4];
  #pragma unroll
  for (int nt = 0; nt < 4; ++nt) oacc[nt] = (f32x4){0.f,0.f,0.f,0.f};

  #pragma unroll 1
  for (int i = 0; i < 3; ++i){
    const float* src = (i==0)?t1:(i==1)?t2:t3;
    int s1 = (i==0)?1:0, s2 = (i==2)?1:2;
    float Treg[4][4];
    #pragma unroll
    for (int nt = 0; nt < 4; ++nt){
      #pragma unroll
      for (int r = 0; r < 4; ++r)
        Treg[nt][r] = src[(size_t)(b*128 + rb + 4*g + r)*N_SEQ + n0 + nt*16 + m];
      *reinterpret_cast<uint2*>(&Xl[(nt*16+m)*XS + rb + 4*g]) =
        make_uint2(pk2(Treg[nt][0], Treg[nt][1]), pk2(Treg[nt][2], Treg[nt][3]));
    }
    __syncthreads();
    stage<2>(Xl, Ul, wqf, Wback, kvf, ksf, s1, s2, b, w, g, m, rb, Treg);  // stage A
    stage<1>(Xl, Ul, wqf, Wback, kvf, ksf, 3, 3, b, w, g, m, rb, Treg);    // stage B (fusion kv)
    // acc += Wout[:, i*128 : i*128+128] @ t_if
    u32 wof[16];
    load_wfrag(Wout, rb + m, 384, i*128, g, wof);
    gemm16(wof, Xl, m, g, oacc);
    __syncthreads();   // before next i overwrites Xl
  }
  #pragma unroll
  for (int nt = 0; nt < 4; ++nt)
    #pragma unroll
    for (int r = 0; r < 4; ++r){
      size_t idx = (size_t)(b*128 + rb + 4*g + r)*N_SEQ + n0 + nt*16 + m;
      outp[idx] = oacc[nt][r] + fs[idx];
    }
}

extern "C" void kernel_launch(void* const* d_in, const int* in_sizes, int n_in,
                              void* d_out, int out_size, void* d_ws, size_t ws_size,
                              hipStream_t stream){
  const float* t1 = (const float*)d_in[0];
  const float* t2 = (const float*)d_in[1];
  const float* t3 = (const float*)d_in[2];
  const float* fs = (const float*)d_in[3];
  const float* Wq = (const float*)d_in[4];
  const float* Wk = (const float*)d_in[5];
  const float* Wv = (const float*)d_in[6];
  const float* Wb = (const float*)d_in[7];
  const float* Wo = (const float*)d_in[8];
  float* outp = (float*)d_out;
  float* ws = (float*)d_ws;
  // ws layout (floats): final KV [65536] | final Ks [4096] | partial KV [16*65536] | partial Ks [16*4096]
  float* kvf = ws;
  float* ksf = ws + 65536;
  float* pkv = ws + 69632;
  float* pks = ws + 69632 + 16*65536;

  k_pass1 <<<dim3(512),  dim3(512), 0, stream>>>(t1, t2, t3, fs, Wk, Wv, pkv, pks);
  k_reduce<<<dim3(272),  dim3(256), 0, stream>>>(pkv, pks, kvf, ksf);
  k_pass2 <<<dim3(2048), dim3(512), 0, stream>>>(t1, t2, t3, fs, Wq, Wb, Wo, kvf, ksf, outp);
}